// Round 6
// baseline (626.323 us; speedup 1.0000x reference)
//
#include <hip/hip_runtime.h>
#include <hip/hip_bf16.h>

#define B_SZ   8
#define S_LEN  4096
#define D_K    128
#define KB     64      // keys per step
#define NTILE  512     // 8 batches x 64 q-tiles, whole-tile scheduling (no split-K)

// LDS strides in shorts. 272 B / 144 B row strides == 16 mod 128 -> benign bank
// patterns for b128 writes and fragment reads (R3/R4-verified).
#define KT_STR 136
#define VT_STR 72
#define PT_STR 72

typedef short  short8  __attribute__((ext_vector_type(8)));
typedef float  floatx4 __attribute__((ext_vector_type(4)));

#define EXP2F(x) exp2f(x)

__device__ __forceinline__ unsigned bfround(float x) {
  unsigned u = __builtin_bit_cast(unsigned, x);
  return (u + 0x7fffu + ((u >> 16) & 1u)) >> 16;
}
__device__ __forceinline__ unsigned bfpack2(float a, float b) {
  return bfround(a) | (bfround(b) << 16);
}

// ======================= fused pre-pass =======================
// blocks [0,2048): K fp32 -> bf16 copy ; [2048,3072): V -> bf16 transpose ;
// block 3072: zero the chunk counter.

__global__ __launch_bounds__(256)
void prepass(const float* __restrict__ K, const float* __restrict__ V,
             unsigned short* __restrict__ Kb, unsigned short* __restrict__ Vt,
             int* __restrict__ cnt) {
  __shared__ float tile[64][65];
  const int bid = blockIdx.x;
  const int t   = threadIdx.x;

  if (bid < 2048) {
    const size_t idx = ((size_t)bid * 256 + t) * 8;
    float4 f0 = *(const float4*)(K + idx);
    float4 f1 = *(const float4*)(K + idx + 4);
    uint4 u;
    u.x = bfpack2(f0.x, f0.y);
    u.y = bfpack2(f0.z, f0.w);
    u.z = bfpack2(f1.x, f1.y);
    u.w = bfpack2(f1.z, f1.w);
    *(uint4*)(Kb + idx) = u;
  } else if (bid < 3072) {
    const int vb  = bid - 2048;
    const int b   = vb >> 7;
    const int rem = vb & 127;
    const int kt  = (rem >> 1) * 64;
    const int dt  = (rem & 1) * 64;
    {
      const int c  = (t & 15) * 4;
      const int r0 = t >> 4;
#pragma unroll
      for (int rr = 0; rr < 4; ++rr) {
        const int r = r0 + rr * 16;
        float4 f = *(const float4*)(V + (size_t)(b * S_LEN + kt + r) * D_K + dt + c);
        tile[r][c]     = f.x;
        tile[r][c + 1] = f.y;
        tile[r][c + 2] = f.z;
        tile[r][c + 3] = f.w;
      }
    }
    __syncthreads();
    {
      const int d  = t >> 2;
      const int k0 = (t & 3) * 16;
#pragma unroll
      for (int j = 0; j < 16; j += 8) {
        uint4 u;
        u.x = bfpack2(tile[k0 + j + 0][d], tile[k0 + j + 1][d]);
        u.y = bfpack2(tile[k0 + j + 2][d], tile[k0 + j + 3][d]);
        u.z = bfpack2(tile[k0 + j + 4][d], tile[k0 + j + 5][d]);
        u.w = bfpack2(tile[k0 + j + 6][d], tile[k0 + j + 7][d]);
        *(uint4*)(Vt + (size_t)(b * D_K + dt + d) * S_LEN + kt + k0 + j) = u;
      }
    }
  } else {
    if (t == 0) cnt[0] = 0;
  }
}

// ======================= worker: whole-tile dynamic LPT =======================
// 512 tiles (b, qi) in descending-qi order via a global atomic queue. Each tile
// is fully processed by one 128-thread block -> normalized O written directly.
// No partials, no combine, no device fences (the R5 killer).

__global__ __launch_bounds__(128, 2)
void attn_worker(const float* __restrict__ Q, const unsigned short* __restrict__ Kb,
                 const unsigned short* __restrict__ Vt, int* __restrict__ cnt,
                 float* __restrict__ O) {
  __shared__ __align__(16) short Klds[KB * KT_STR];     // 17408 B
  __shared__ __align__(16) short Vtlds[D_K * VT_STR];   // 18432 B
  __shared__ __align__(16) short Plds[2 * 16 * PT_STR]; //  4608 B  (40448 -> 4 blocks/CU)
  __shared__ int s_chunk;

  const int tid  = threadIdx.x;
  const int lane = tid & 63;
  const int w    = tid >> 6;
  const int l15  = lane & 15;
  const int quad = lane >> 4;

  const int kr0 = tid >> 4;
  const int kc  = (tid & 15) * 8;
  const int vr0 = tid >> 3;
  const int vc  = (tid & 7) * 8;

  const float CSC = 0.12752041f;    // log2(e)/sqrt(128)

  for (;;) {
    if (tid == 0) s_chunk = atomicAdd(&cnt[0], 1);
    __syncthreads();
    const int tidx = s_chunk;
    __syncthreads();
    if (tidx >= NTILE) break;

    const int qi = 63 - (tidx >> 3);   // descending size = LPT
    const int b  = tidx & 7;
    const int q0 = qi * 64;
    const int nsteps = qi + 1;

    // ---- Q fragments (B-operand: n=l15=query, k=quad*8+j=d) ----
    short8 bq[2][4];
    int qg[2];
#pragma unroll
    for (int sub = 0; sub < 2; ++sub) {
      qg[sub] = q0 + w * 32 + sub * 16 + l15;
      const float* qrow = Q + (size_t)(b * S_LEN + qg[sub]) * D_K + quad * 8;
#pragma unroll
      for (int kd = 0; kd < 4; ++kd) {
        float4 f0 = *(const float4*)(qrow + kd * 32);
        float4 f1 = *(const float4*)(qrow + kd * 32 + 4);
        union { short8 s; unsigned u[4]; } t;
        t.u[0] = bfpack2(f0.x, f0.y);
        t.u[1] = bfpack2(f0.z, f0.w);
        t.u[2] = bfpack2(f1.x, f1.y);
        t.u[3] = bfpack2(f1.z, f1.w);
        bq[sub][kd] = t.s;
      }
    }

    floatx4 acc[2][8];
#pragma unroll
    for (int sub = 0; sub < 2; ++sub)
#pragma unroll
      for (int nc = 0; nc < 8; ++nc) acc[sub][nc] = (floatx4){0.f, 0.f, 0.f, 0.f};
    float m_run[2] = {-1e30f, -1e30f}, l_run[2] = {0.f, 0.f};

    const unsigned short* kbase = Kb + (size_t)(b * S_LEN) * D_K;
    const unsigned short* vbase = Vt + (size_t)(b * D_K) * S_LEN;

    // ---- preload step 0 tiles into registers ----
    uint4 rk[8], rv[8];
#pragma unroll
    for (int i = 0; i < 8; ++i)
      rk[i] = *(const uint4*)(kbase + (size_t)(kr0 + i * 8) * D_K + kc);
#pragma unroll
    for (int i = 0; i < 8; ++i)
      rv[i] = *(const uint4*)(vbase + (size_t)(vr0 + i * 16) * S_LEN + vc);

    for (int s = 0; s < nsteps; ++s) {
      // ---- stage prefetched tile to LDS ----
#pragma unroll
      for (int i = 0; i < 8; ++i)
        *(uint4*)(&Klds[(kr0 + i * 8) * KT_STR + kc]) = rk[i];
#pragma unroll
      for (int i = 0; i < 8; ++i)
        *(uint4*)(&Vtlds[(vr0 + i * 16) * VT_STR + vc]) = rv[i];
      __syncthreads();

      // ---- prefetch next step; clobber pins the loads here (issue early,
      //      complete during the MFMA/softmax work below) ----
      if (s + 1 < nsteps) {
        const int kt2 = (s + 1) * KB;
#pragma unroll
        for (int i = 0; i < 8; ++i)
          rk[i] = *(const uint4*)(kbase + (size_t)(kt2 + kr0 + i * 8) * D_K + kc);
#pragma unroll
        for (int i = 0; i < 8; ++i)
          rv[i] = *(const uint4*)(vbase + (size_t)(vr0 + i * 16) * S_LEN + kt2 + vc);
        __asm__ __volatile__("" ::: "memory");
      }

      const int kt = s * KB;

      // ---- S^T = K*Q^T, both subtiles share each A-frag read ----
      floatx4 st[2][4];
#pragma unroll
      for (int kf = 0; kf < 4; ++kf) {
        floatx4 c0 = (floatx4){0.f, 0.f, 0.f, 0.f};
        floatx4 c1 = (floatx4){0.f, 0.f, 0.f, 0.f};
#pragma unroll
        for (int kd = 0; kd < 4; ++kd) {
          short8 a = *(const short8*)(&Klds[(kf * 16 + l15) * KT_STR + kd * 32 + quad * 8]);
          c0 = __builtin_amdgcn_mfma_f32_16x16x32_bf16(a, bq[0][kd], c0, 0, 0, 0);
          c1 = __builtin_amdgcn_mfma_f32_16x16x32_bf16(a, bq[1][kd], c1, 0, 0, 0);
        }
        st[0][kf] = c0;
        st[1][kf] = c1;
      }

      // ---- causal mask (diagonal step only) ----
      if (s == qi) {
#pragma unroll
        for (int sub = 0; sub < 2; ++sub)
#pragma unroll
          for (int kf = 0; kf < 4; ++kf)
#pragma unroll
            for (int r = 0; r < 4; ++r) {
              int key = kt + kf * 16 + quad * 4 + r;
              if (key > qg[sub]) st[sub][kf][r] = -1e30f;
            }
      }

      // ---- online softmax + P roundtrip + rescale ----
      short8 pa[2][2];
#pragma unroll
      for (int sub = 0; sub < 2; ++sub) {
        float mx = st[sub][0][0];
#pragma unroll
        for (int kf = 0; kf < 4; ++kf)
#pragma unroll
          for (int r = 0; r < 4; ++r) mx = fmaxf(mx, st[sub][kf][r]);
        mx = fmaxf(mx, __shfl_xor(mx, 16, 64));
        mx = fmaxf(mx, __shfl_xor(mx, 32, 64));
        const float m_new = fmaxf(m_run[sub], mx);
        const float alpha = EXP2F((m_run[sub] - m_new) * CSC);

        float p[4][4];
        float tsum = 0.f;
#pragma unroll
        for (int kf = 0; kf < 4; ++kf)
#pragma unroll
          for (int r = 0; r < 4; ++r) {
            p[kf][r] = EXP2F((st[sub][kf][r] - m_new) * CSC);
            tsum += p[kf][r];
          }
        tsum += __shfl_xor(tsum, 16, 64);
        tsum += __shfl_xor(tsum, 32, 64);
        l_run[sub] = l_run[sub] * alpha + tsum;
        m_run[sub] = m_new;

#pragma unroll
        for (int r = 0; r < 4; ++r) {
          const float ar = __shfl(alpha, quad * 4 + r, 64);
#pragma unroll
          for (int nc = 0; nc < 8; ++nc) acc[sub][nc][r] *= ar;
        }

        short* pw = &Plds[(w * 16 + l15) * PT_STR];
#pragma unroll
        for (int kf = 0; kf < 4; ++kf) {
          uint2 u;
          u.x = bfpack2(p[kf][0], p[kf][1]);
          u.y = bfpack2(p[kf][2], p[kf][3]);
          *(uint2*)(&pw[kf * 16 + quad * 4]) = u;
        }
        __asm__ __volatile__("" ::: "memory");
        pa[sub][0] = *(const short8*)(&pw[quad * 8]);
        pa[sub][1] = *(const short8*)(&pw[32 + quad * 8]);
        __asm__ __volatile__("" ::: "memory");
      }

      // ---- O += P*V, each B-frag read shared by both subtiles ----
#pragma unroll
      for (int nc = 0; nc < 8; ++nc) {
        short8 bv0 = *(const short8*)(&Vtlds[(nc * 16 + l15) * VT_STR + quad * 8]);
        short8 bv1 = *(const short8*)(&Vtlds[(nc * 16 + l15) * VT_STR + 32 + quad * 8]);
        acc[0][nc] = __builtin_amdgcn_mfma_f32_16x16x32_bf16(pa[0][0], bv0, acc[0][nc], 0, 0, 0);
        acc[0][nc] = __builtin_amdgcn_mfma_f32_16x16x32_bf16(pa[0][1], bv1, acc[0][nc], 0, 0, 0);
        acc[1][nc] = __builtin_amdgcn_mfma_f32_16x16x32_bf16(pa[1][0], bv0, acc[1][nc], 0, 0, 0);
        acc[1][nc] = __builtin_amdgcn_mfma_f32_16x16x32_bf16(pa[1][1], bv1, acc[1][nc], 0, 0, 0);
      }
      __syncthreads();
    }

    // ---- epilogue: normalized O, written directly ----
#pragma unroll
    for (int sub = 0; sub < 2; ++sub) {
#pragma unroll
      for (int r = 0; r < 4; ++r) {
        const float lr  = __shfl(l_run[sub], quad * 4 + r, 64);
        const float inv = 1.0f / lr;
        const int qout  = q0 + w * 32 + sub * 16 + quad * 4 + r;
        float* op = O + (size_t)(b * S_LEN + qout) * D_K + l15;
#pragma unroll
        for (int nc = 0; nc < 8; ++nc) op[nc * 16] = acc[sub][nc][r] * inv;
      }
    }
  }
}

// ======================= fallback (R2 kernel, known-good) =======================

__global__ __launch_bounds__(256, 2)
void attn_fwd_fb(const float* __restrict__ Q, const float* __restrict__ K,
                 const float* __restrict__ V, float* __restrict__ O) {
  __shared__ __align__(16) short Klds[KB * KT_STR];
  __shared__ __align__(16) short Vtlds[D_K * VT_STR];
  __shared__ __align__(16) short Plds[4 * 16 * PT_STR];

  const int tid  = threadIdx.x;
  const int lane = tid & 63;
  const int w    = tid >> 6;
  const int l15  = lane & 15;
  const int quad = lane >> 4;

  const int bid = blockIdx.x;
  const int b   = bid & 7;
  const int qi  = 63 - (bid >> 3);
  const int q0  = qi * 64;

  const float CSC = 0.12752041f;

  const int    qg   = q0 + w * 16 + l15;
  const float* qrow = Q + (size_t)(b * S_LEN + qg) * D_K + quad * 8;
  short8 bq[4];
#pragma unroll
  for (int kd = 0; kd < 4; ++kd) {
    float4 f0 = *(const float4*)(qrow + kd * 32);
    float4 f1 = *(const float4*)(qrow + kd * 32 + 4);
    union { short8 s; unsigned u[4]; } t;
    t.u[0] = bfpack2(f0.x, f0.y);
    t.u[1] = bfpack2(f0.z, f0.w);
    t.u[2] = bfpack2(f1.x, f1.y);
    t.u[3] = bfpack2(f1.z, f1.w);
    bq[kd] = t.s;
  }

  floatx4 acc[8];
#pragma unroll
  for (int nc = 0; nc < 8; ++nc) acc[nc] = (floatx4){0.f, 0.f, 0.f, 0.f};
  float m_run = -1e30f, l_run = 0.f;

  const int d4 = tid & 31;
  const int kq = tid >> 5;
  const int nsteps = qi + 1;

  for (int s = 0; s < nsteps; ++s) {
    const int kt = s * KB;
#pragma unroll
    for (int r2 = 0; r2 < 2; ++r2) {
      const int row = r2 * 32 + kq * 4;
      const float* kp = K + (size_t)(b * S_LEN + kt + row) * D_K + d4 * 4;
      const float* vp = V + (size_t)(b * S_LEN + kt + row) * D_K + d4 * 4;
      float4 fk[4], fv[4];
#pragma unroll
      for (int i = 0; i < 4; ++i) {
        fk[i] = *(const float4*)(kp + i * D_K);
        fv[i] = *(const float4*)(vp + i * D_K);
      }
#pragma unroll
      for (int i = 0; i < 4; ++i) {
        uint2 u;
        u.x = bfpack2(fk[i].x, fk[i].y);
        u.y = bfpack2(fk[i].z, fk[i].w);
        *(uint2*)(&Klds[(row + i) * KT_STR + d4 * 4]) = u;
      }
#pragma unroll
      for (int c = 0; c < 4; ++c) {
        float e0 = ((const float*)&fv[0])[c];
        float e1 = ((const float*)&fv[1])[c];
        float e2 = ((const float*)&fv[2])[c];
        float e3 = ((const float*)&fv[3])[c];
        uint2 u;
        u.x = bfpack2(e0, e1);
        u.y = bfpack2(e2, e3);
        *(uint2*)(&Vtlds[(d4 * 4 + c) * VT_STR + row]) = u;
      }
    }
    __syncthreads();

    floatx4 st[4];
#pragma unroll
    for (int kf = 0; kf < 4; ++kf) {
      floatx4 c = (floatx4){0.f, 0.f, 0.f, 0.f};
#pragma unroll
      for (int kd = 0; kd < 4; ++kd) {
        short8 a = *(const short8*)(&Klds[(kf * 16 + l15) * KT_STR + kd * 32 + quad * 8]);
        c = __builtin_amdgcn_mfma_f32_16x16x32_bf16(a, bq[kd], c, 0, 0, 0);
      }
      st[kf] = c;
    }

    if (s == nsteps - 1) {
#pragma unroll
      for (int kf = 0; kf < 4; ++kf)
#pragma unroll
        for (int r = 0; r < 4; ++r) {
          int key = kt + kf * 16 + quad * 4 + r;
          if (key > qg) st[kf][r] = -1e30f;
        }
    }

    float mx = st[0][0];
#pragma unroll
    for (int kf = 0; kf < 4; ++kf)
#pragma unroll
      for (int r = 0; r < 4; ++r) mx = fmaxf(mx, st[kf][r]);
    mx = fmaxf(mx, __shfl_xor(mx, 16, 64));
    mx = fmaxf(mx, __shfl_xor(mx, 32, 64));
    const float m_new = fmaxf(m_run, mx);
    const float alpha = EXP2F((m_run - m_new) * CSC);

    float p[4][4];
    float tsum = 0.f;
#pragma unroll
    for (int kf = 0; kf < 4; ++kf)
#pragma unroll
      for (int r = 0; r < 4; ++r) {
        p[kf][r] = EXP2F((st[kf][r] - m_new) * CSC);
        tsum += p[kf][r];
      }
    tsum += __shfl_xor(tsum, 16, 64);
    tsum += __shfl_xor(tsum, 32, 64);
    l_run = l_run * alpha + tsum;
    m_run = m_new;

#pragma unroll
    for (int r = 0; r < 4; ++r) {
      const float ar = __shfl(alpha, quad * 4 + r, 64);
#pragma unroll
      for (int nc = 0; nc < 8; ++nc) acc[nc][r] *= ar;
    }

    short* pw = &Plds[(w * 16 + l15) * PT_STR];
#pragma unroll
    for (int kf = 0; kf < 4; ++kf) {
      uint2 u;
      u.x = bfpack2(p[kf][0], p[kf][1]);
      u.y = bfpack2(p[kf][2], p[kf][3]);
      *(uint2*)(&pw[kf * 16 + quad * 4]) = u;
    }
    __asm__ __volatile__("" ::: "memory");
    short8 pa0 = *(const short8*)(&pw[quad * 8]);
    short8 pa1 = *(const short8*)(&pw[32 + quad * 8]);

#pragma unroll
    for (int nc = 0; nc < 8; ++nc) {
      short8 bv0 = *(const short8*)(&Vtlds[(nc * 16 + l15) * VT_STR + quad * 8]);
      acc[nc] = __builtin_amdgcn_mfma_f32_16x16x32_bf16(pa0, bv0, acc[nc], 0, 0, 0);
      short8 bv1 = *(const short8*)(&Vtlds[(nc * 16 + l15) * VT_STR + 32 + quad * 8]);
      acc[nc] = __builtin_amdgcn_mfma_f32_16x16x32_bf16(pa1, bv1, acc[nc], 0, 0, 0);
    }
    __syncthreads();
  }

#pragma unroll
  for (int r = 0; r < 4; ++r) {
    const float lr  = __shfl(l_run, quad * 4 + r, 64);
    const float inv = 1.0f / lr;
    const int qout  = q0 + w * 16 + quad * 4 + r;
    float* op = O + (size_t)(b * S_LEN + qout) * D_K + l15;
#pragma unroll
    for (int nc = 0; nc < 8; ++nc) op[nc * 16] = acc[nc][r] * inv;
  }
}

// ======================= launch =======================

extern "C" void kernel_launch(void* const* d_in, const int* in_sizes, int n_in,
                              void* d_out, int out_size, void* d_ws, size_t ws_size,
                              hipStream_t stream) {
  const float* Q = (const float*)d_in[0];
  const float* K = (const float*)d_in[1];
  const float* V = (const float*)d_in[2];
  float* O = (float*)d_out;

  const size_t elems = (size_t)B_SZ * S_LEN * D_K;   // 4.19M

  // ws layout (bytes): [0]=chunk counter ; 4096: Kb bf16 ; +8.39MB: Vt bf16
  const size_t off_kb = 4096;
  const size_t off_vt = off_kb + elems * 2;
  const size_t need   = off_vt + elems * 2;          // ~16.8 MB

  if (ws_size >= need) {
    char* ws = (char*)d_ws;
    int*            cnt = (int*)ws;
    unsigned short* Kb  = (unsigned short*)(ws + off_kb);
    unsigned short* Vt  = (unsigned short*)(ws + off_vt);

    prepass<<<dim3(3073), dim3(256), 0, stream>>>(K, V, Kb, Vt, cnt);
    attn_worker<<<dim3(1024), dim3(128), 0, stream>>>(Q, Kb, Vt, cnt, O);
  } else {
    attn_fwd_fb<<<dim3(512), dim3(256), 0, stream>>>(Q, K, V, O);
  }
}

// Round 7
// 242.968 us; speedup vs baseline: 2.5778x; 2.5778x over previous
//
#include <hip/hip_runtime.h>
#include <hip/hip_bf16.h>

#define B_SZ   8
#define S_LEN  4096
#define D_K    128
#define KB     64      // keys per step
#define PT_STR 72      // P scratch row stride (shorts)

typedef short  short8  __attribute__((ext_vector_type(8)));
typedef float  floatx4 __attribute__((ext_vector_type(4)));

#define EXP2F(x) exp2f(x)

__device__ __forceinline__ unsigned bfround(float x) {
  unsigned u = __builtin_bit_cast(unsigned, x);
  return (u + 0x7fffu + ((u >> 16) & 1u)) >> 16;
}
__device__ __forceinline__ unsigned bfpack2(float a, float b) {
  return bfround(a) | (bfround(b) << 16);
}

// ======================= fused pre-pass =======================
// blocks [0,2048): K fp32 -> bf16 copy ; [2048,3072): V -> bf16 transpose [b][d][s]

__global__ __launch_bounds__(256)
void prepass(const float* __restrict__ K, const float* __restrict__ V,
             unsigned short* __restrict__ Kb, unsigned short* __restrict__ Vt) {
  __shared__ float tile[64][65];
  const int bid = blockIdx.x;
  const int t   = threadIdx.x;

  if (bid < 2048) {
    const size_t idx = ((size_t)bid * 256 + t) * 8;
    float4 f0 = *(const float4*)(K + idx);
    float4 f1 = *(const float4*)(K + idx + 4);
    uint4 u;
    u.x = bfpack2(f0.x, f0.y);
    u.y = bfpack2(f0.z, f0.w);
    u.z = bfpack2(f1.x, f1.y);
    u.w = bfpack2(f1.z, f1.w);
    *(uint4*)(Kb + idx) = u;
  } else {
    const int vb  = bid - 2048;
    const int b   = vb >> 7;
    const int rem = vb & 127;
    const int kt  = (rem >> 1) * 64;
    const int dt  = (rem & 1) * 64;
    {
      const int c  = (t & 15) * 4;
      const int r0 = t >> 4;
#pragma unroll
      for (int rr = 0; rr < 4; ++rr) {
        const int r = r0 + rr * 16;
        float4 f = *(const float4*)(V + (size_t)(b * S_LEN + kt + r) * D_K + dt + c);
        tile[r][c]     = f.x;
        tile[r][c + 1] = f.y;
        tile[r][c + 2] = f.z;
        tile[r][c + 3] = f.w;
      }
    }
    __syncthreads();
    {
      const int d  = t >> 2;
      const int k0 = (t & 3) * 16;
#pragma unroll
      for (int j = 0; j < 16; j += 8) {
        uint4 u;
        u.x = bfpack2(tile[k0 + j + 0][d], tile[k0 + j + 1][d]);
        u.y = bfpack2(tile[k0 + j + 2][d], tile[k0 + j + 3][d]);
        u.z = bfpack2(tile[k0 + j + 4][d], tile[k0 + j + 5][d]);
        u.w = bfpack2(tile[k0 + j + 6][d], tile[k0 + j + 7][d]);
        *(uint4*)(Vt + (size_t)(b * D_K + dt + d) * S_LEN + kt + k0 + j) = u;
      }
    }
  }
}

// ======================= worker: 1 wave / 32-query tile =======================
// No K/V LDS staging: A-frags (K) and B-frags (Vt) load global->register with
// fully-coalesced fragment addressing (16 rows x 64 B per wave-load). No
// __syncthreads anywhere. LDS = per-wave P-roundtrip only (2304 B).
// Balanced static decode: co-resident groups {g,g+256,g+512,g+768} sum to a
// constant 130 key-steps per CU (round-robin dispatch assumption).

__global__ __launch_bounds__(64, 1)
void attn_worker(const float* __restrict__ Q, const unsigned short* __restrict__ Kb,
                 const unsigned short* __restrict__ Vt, float* __restrict__ O) {
  __shared__ __align__(16) short Plds[16 * PT_STR];   // 2304 B, wave-private

  const int lane = threadIdx.x;
  const int l15  = lane & 15;
  const int quad = lane >> 4;

  // ---- balanced decode: qj per residency-round r ----
  const int g  = blockIdx.x & 255;
  const int r  = blockIdx.x >> 8;
  const int b  = g & 7;
  const int h  = g >> 3;
  const int qj = (r == 0) ? (127 - h) : (r == 1) ? (64 + h) : (r == 2) ? (63 - h) : h;

  const int q0     = qj * 32;
  const int nsteps = (qj >> 1) + 1;   // keys [0, 32*qj+32) covered by 64-key steps

  const float CSC = 0.12752041f;      // log2(e)/sqrt(128)

  // ---- Q fragments (B-operand: n=l15=query, k=quad*8+j=d) ----
  short8 bq[2][4];
  int qg[2];
#pragma unroll
  for (int sub = 0; sub < 2; ++sub) {
    qg[sub] = q0 + sub * 16 + l15;
    const float* qrow = Q + (size_t)(b * S_LEN + qg[sub]) * D_K + quad * 8;
#pragma unroll
    for (int kd = 0; kd < 4; ++kd) {
      float4 f0 = *(const float4*)(qrow + kd * 32);
      float4 f1 = *(const float4*)(qrow + kd * 32 + 4);
      union { short8 s; unsigned u[4]; } t;
      t.u[0] = bfpack2(f0.x, f0.y);
      t.u[1] = bfpack2(f0.z, f0.w);
      t.u[2] = bfpack2(f1.x, f1.y);
      t.u[3] = bfpack2(f1.z, f1.w);
      bq[sub][kd] = t.s;
    }
  }

  floatx4 acc[2][8];
#pragma unroll
  for (int sub = 0; sub < 2; ++sub)
#pragma unroll
    for (int nc = 0; nc < 8; ++nc) acc[sub][nc] = (floatx4){0.f, 0.f, 0.f, 0.f};
  float m_run[2] = {-1e30f, -1e30f}, l_run[2] = {0.f, 0.f};

  // per-lane invariant fragment bases
  const unsigned short* kl = Kb + (size_t)b * S_LEN * D_K + (size_t)l15 * D_K + quad * 8;
  const unsigned short* vl = Vt + (size_t)b * D_K * S_LEN + (size_t)l15 * S_LEN + quad * 8;

  // ---- preload step-0 K A-frags ----
  short8 ak[4][4];
#pragma unroll
  for (int kf = 0; kf < 4; ++kf)
#pragma unroll
    for (int kd = 0; kd < 4; ++kd)
      ak[kf][kd] = *(const short8*)(kl + (size_t)(kf * 16) * D_K + kd * 32);

  for (int s = 0; s < nsteps; ++s) {
    const int kt = s * KB;

    // ---- issue V B-frag loads (used after softmax; latency covered) ----
    short8 bv[8][2];
#pragma unroll
    for (int nc = 0; nc < 8; ++nc)
#pragma unroll
      for (int c = 0; c < 2; ++c)
        bv[nc][c] = *(const short8*)(vl + (size_t)(nc * 16) * S_LEN + kt + c * 32);

    // ---- S^T = K*Q^T (C: col=l15=query, row=quad*4+reg=key) ----
    floatx4 st[2][4];
#pragma unroll
    for (int kf = 0; kf < 4; ++kf) {
      floatx4 c0 = (floatx4){0.f, 0.f, 0.f, 0.f};
      floatx4 c1 = (floatx4){0.f, 0.f, 0.f, 0.f};
#pragma unroll
      for (int kd = 0; kd < 4; ++kd) {
        c0 = __builtin_amdgcn_mfma_f32_16x16x32_bf16(ak[kf][kd], bq[0][kd], c0, 0, 0, 0);
        c1 = __builtin_amdgcn_mfma_f32_16x16x32_bf16(ak[kf][kd], bq[1][kd], c1, 0, 0, 0);
      }
      st[0][kf] = c0;
      st[1][kf] = c1;
    }

    // ---- prefetch next step's K A-frags (covered by softmax + PV) ----
    if (s + 1 < nsteps) {
      const int kt2 = kt + KB;
#pragma unroll
      for (int kf = 0; kf < 4; ++kf)
#pragma unroll
        for (int kd = 0; kd < 4; ++kd)
          ak[kf][kd] = *(const short8*)(kl + (size_t)(kt2 + kf * 16) * D_K + kd * 32);
    }

    // ---- causal mask (only the last step can touch keys > q) ----
    if (s == nsteps - 1) {
#pragma unroll
      for (int sub = 0; sub < 2; ++sub)
#pragma unroll
        for (int kf = 0; kf < 4; ++kf)
#pragma unroll
          for (int rr = 0; rr < 4; ++rr) {
            int key = kt + kf * 16 + quad * 4 + rr;
            if (key > qg[sub]) st[sub][kf][rr] = -1e30f;
          }
    }

    // ---- online softmax + P roundtrip + rescale, per subtile ----
    short8 pa[2][2];
#pragma unroll
    for (int sub = 0; sub < 2; ++sub) {
      float mx = st[sub][0][0];
#pragma unroll
      for (int kf = 0; kf < 4; ++kf)
#pragma unroll
        for (int rr = 0; rr < 4; ++rr) mx = fmaxf(mx, st[sub][kf][rr]);
      mx = fmaxf(mx, __shfl_xor(mx, 16, 64));
      mx = fmaxf(mx, __shfl_xor(mx, 32, 64));
      const float m_new = fmaxf(m_run[sub], mx);
      const float alpha = EXP2F((m_run[sub] - m_new) * CSC);

      float p[4][4];
      float tsum = 0.f;
#pragma unroll
      for (int kf = 0; kf < 4; ++kf)
#pragma unroll
        for (int rr = 0; rr < 4; ++rr) {
          p[kf][rr] = EXP2F((st[sub][kf][rr] - m_new) * CSC);
          tsum += p[kf][rr];
        }
      tsum += __shfl_xor(tsum, 16, 64);
      tsum += __shfl_xor(tsum, 32, 64);
      l_run[sub] = l_run[sub] * alpha + tsum;
      m_run[sub] = m_new;

#pragma unroll
      for (int rr = 0; rr < 4; ++rr) {
        const float ar = __shfl(alpha, quad * 4 + rr, 64);
#pragma unroll
        for (int nc = 0; nc < 8; ++nc) acc[sub][nc][rr] *= ar;
      }

      // P: C-layout -> A-layout via wave-private LDS roundtrip
      short* pw = &Plds[l15 * PT_STR];
#pragma unroll
      for (int kf = 0; kf < 4; ++kf) {
        uint2 u;
        u.x = bfpack2(p[kf][0], p[kf][1]);
        u.y = bfpack2(p[kf][2], p[kf][3]);
        *(uint2*)(&pw[kf * 16 + quad * 4]) = u;
      }
      __asm__ __volatile__("" ::: "memory");
      pa[sub][0] = *(const short8*)(&pw[quad * 8]);
      pa[sub][1] = *(const short8*)(&pw[32 + quad * 8]);
      __asm__ __volatile__("" ::: "memory");
    }

    // ---- O += P*V with register B-frags ----
#pragma unroll
    for (int nc = 0; nc < 8; ++nc) {
      acc[0][nc] = __builtin_amdgcn_mfma_f32_16x16x32_bf16(pa[0][0], bv[nc][0], acc[0][nc], 0, 0, 0);
      acc[0][nc] = __builtin_amdgcn_mfma_f32_16x16x32_bf16(pa[0][1], bv[nc][1], acc[0][nc], 0, 0, 0);
      acc[1][nc] = __builtin_amdgcn_mfma_f32_16x16x32_bf16(pa[1][0], bv[nc][0], acc[1][nc], 0, 0, 0);
      acc[1][nc] = __builtin_amdgcn_mfma_f32_16x16x32_bf16(pa[1][1], bv[nc][1], acc[1][nc], 0, 0, 0);
    }
  }

  // ---- epilogue: normalized O ----
#pragma unroll
  for (int sub = 0; sub < 2; ++sub) {
#pragma unroll
    for (int rr = 0; rr < 4; ++rr) {
      const float lr  = __shfl(l_run[sub], quad * 4 + rr, 64);
      const float inv = 1.0f / lr;
      const int qout  = q0 + sub * 16 + quad * 4 + rr;
      float* op = O + (size_t)(b * S_LEN + qout) * D_K + l15;
#pragma unroll
      for (int nc = 0; nc < 8; ++nc) op[nc * 16] = acc[sub][nc][rr] * inv;
    }
  }
}

// ======================= fallback (R2 kernel, known-good) =======================

#define KT_STR 136
#define VT_STR 72

__global__ __launch_bounds__(256, 2)
void attn_fwd_fb(const float* __restrict__ Q, const float* __restrict__ K,
                 const float* __restrict__ V, float* __restrict__ O) {
  __shared__ __align__(16) short Klds[KB * KT_STR];
  __shared__ __align__(16) short Vtlds[D_K * VT_STR];
  __shared__ __align__(16) short Plds2[4 * 16 * PT_STR];

  const int tid  = threadIdx.x;
  const int lane = tid & 63;
  const int w    = tid >> 6;
  const int l15  = lane & 15;
  const int quad = lane >> 4;

  const int bid = blockIdx.x;
  const int b   = bid & 7;
  const int qi  = 63 - (bid >> 3);
  const int q0  = qi * 64;

  const float CSC = 0.12752041f;

  const int    qg   = q0 + w * 16 + l15;
  const float* qrow = Q + (size_t)(b * S_LEN + qg) * D_K + quad * 8;
  short8 bq[4];
#pragma unroll
  for (int kd = 0; kd < 4; ++kd) {
    float4 f0 = *(const float4*)(qrow + kd * 32);
    float4 f1 = *(const float4*)(qrow + kd * 32 + 4);
    union { short8 s; unsigned u[4]; } t;
    t.u[0] = bfpack2(f0.x, f0.y);
    t.u[1] = bfpack2(f0.z, f0.w);
    t.u[2] = bfpack2(f1.x, f1.y);
    t.u[3] = bfpack2(f1.z, f1.w);
    bq[kd] = t.s;
  }

  floatx4 acc[8];
#pragma unroll
  for (int nc = 0; nc < 8; ++nc) acc[nc] = (floatx4){0.f, 0.f, 0.f, 0.f};
  float m_run = -1e30f, l_run = 0.f;

  const int d4 = tid & 31;
  const int kq = tid >> 5;
  const int nsteps = qi + 1;

  for (int s = 0; s < nsteps; ++s) {
    const int kt = s * KB;
#pragma unroll
    for (int r2 = 0; r2 < 2; ++r2) {
      const int row = r2 * 32 + kq * 4;
      const float* kp = K + (size_t)(b * S_LEN + kt + row) * D_K + d4 * 4;
      const float* vp = V + (size_t)(b * S_LEN + kt + row) * D_K + d4 * 4;
      float4 fk[4], fv[4];
#pragma unroll
      for (int i = 0; i < 4; ++i) {
        fk[i] = *(const float4*)(kp + i * D_K);
        fv[i] = *(const float4*)(vp + i * D_K);
      }
#pragma unroll
      for (int i = 0; i < 4; ++i) {
        uint2 u;
        u.x = bfpack2(fk[i].x, fk[i].y);
        u.y = bfpack2(fk[i].z, fk[i].w);
        *(uint2*)(&Klds[(row + i) * KT_STR + d4 * 4]) = u;
      }
#pragma unroll
      for (int c = 0; c < 4; ++c) {
        float e0 = ((const float*)&fv[0])[c];
        float e1 = ((const float*)&fv[1])[c];
        float e2 = ((const float*)&fv[2])[c];
        float e3 = ((const float*)&fv[3])[c];
        uint2 u;
        u.x = bfpack2(e0, e1);
        u.y = bfpack2(e2, e3);
        *(uint2*)(&Vtlds[(d4 * 4 + c) * VT_STR + row]) = u;
      }
    }
    __syncthreads();

    floatx4 st[4];
#pragma unroll
    for (int kf = 0; kf < 4; ++kf) {
      floatx4 c = (floatx4){0.f, 0.f, 0.f, 0.f};
#pragma unroll
      for (int kd = 0; kd < 4; ++kd) {
        short8 a = *(const short8*)(&Klds[(kf * 16 + l15) * KT_STR + kd * 32 + quad * 8]);
        c = __builtin_amdgcn_mfma_f32_16x16x32_bf16(a, bq[kd], c, 0, 0, 0);
      }
      st[kf] = c;
    }

    if (s == nsteps - 1) {
#pragma unroll
      for (int kf = 0; kf < 4; ++kf)
#pragma unroll
        for (int rr = 0; rr < 4; ++rr) {
          int key = kt + kf * 16 + quad * 4 + rr;
          if (key > qg) st[kf][rr] = -1e30f;
        }
    }

    float mx = st[0][0];
#pragma unroll
    for (int kf = 0; kf < 4; ++kf)
#pragma unroll
      for (int rr = 0; rr < 4; ++rr) mx = fmaxf(mx, st[kf][rr]);
    mx = fmaxf(mx, __shfl_xor(mx, 16, 64));
    mx = fmaxf(mx, __shfl_xor(mx, 32, 64));
    const float m_new = fmaxf(m_run, mx);
    const float alpha = EXP2F((m_run - m_new) * CSC);

    float p[4][4];
    float tsum = 0.f;
#pragma unroll
    for (int kf = 0; kf < 4; ++kf)
#pragma unroll
      for (int rr = 0; rr < 4; ++rr) {
        p[kf][rr] = EXP2F((st[kf][rr] - m_new) * CSC);
        tsum += p[kf][rr];
      }
    tsum += __shfl_xor(tsum, 16, 64);
    tsum += __shfl_xor(tsum, 32, 64);
    l_run = l_run * alpha + tsum;
    m_run = m_new;

#pragma unroll
    for (int rr = 0; rr < 4; ++rr) {
      const float ar = __shfl(alpha, quad * 4 + rr, 64);
#pragma unroll
      for (int nc = 0; nc < 8; ++nc) acc[nc][rr] *= ar;
    }

    short* pw = &Plds2[(w * 16 + l15) * PT_STR];
#pragma unroll
    for (int kf = 0; kf < 4; ++kf) {
      uint2 u;
      u.x = bfpack2(p[kf][0], p[kf][1]);
      u.y = bfpack2(p[kf][2], p[kf][3]);
      *(uint2*)(&pw[kf * 16 + quad * 4]) = u;
    }
    __asm__ __volatile__("" ::: "memory");
    short8 pa0 = *(const short8*)(&pw[quad * 8]);
    short8 pa1 = *(const short8*)(&pw[32 + quad * 8]);

#pragma unroll
    for (int nc = 0; nc < 8; ++nc) {
      short8 bv0 = *(const short8*)(&Vtlds[(nc * 16 + l15) * VT_STR + quad * 8]);
      acc[nc] = __builtin_amdgcn_mfma_f32_16x16x32_bf16(pa0, bv0, acc[nc], 0, 0, 0);
      short8 bv1 = *(const short8*)(&Vtlds[(nc * 16 + l15) * VT_STR + 32 + quad * 8]);
      acc[nc] = __builtin_amdgcn_mfma_f32_16x16x32_bf16(pa1, bv1, acc[nc], 0, 0, 0);
    }
    __syncthreads();
  }

#pragma unroll
  for (int rr = 0; rr < 4; ++rr) {
    const float lr  = __shfl(l_run, quad * 4 + rr, 64);
    const float inv = 1.0f / lr;
    const int qout  = q0 + w * 16 + quad * 4 + rr;
    float* op = O + (size_t)(b * S_LEN + qout) * D_K + l15;
#pragma unroll
    for (int nc = 0; nc < 8; ++nc) op[nc * 16] = acc[nc][rr] * inv;
  }
}

// ======================= launch =======================

extern "C" void kernel_launch(void* const* d_in, const int* in_sizes, int n_in,
                              void* d_out, int out_size, void* d_ws, size_t ws_size,
                              hipStream_t stream) {
  const float* Q = (const float*)d_in[0];
  const float* K = (const float*)d_in[1];
  const float* V = (const float*)d_in[2];
  float* O = (float*)d_out;

  const size_t elems = (size_t)B_SZ * S_LEN * D_K;   // 4.19M

  const size_t off_kb = 0;
  const size_t off_vt = off_kb + elems * 2;
  const size_t need   = off_vt + elems * 2;          // ~16.8 MB

  if (ws_size >= need) {
    char* ws = (char*)d_ws;
    unsigned short* Kb = (unsigned short*)(ws + off_kb);
    unsigned short* Vt = (unsigned short*)(ws + off_vt);

    prepass<<<dim3(3072), dim3(256), 0, stream>>>(K, V, Kb, Vt);
    attn_worker<<<dim3(1024), dim3(64), 0, stream>>>(Q, Kb, Vt, O);
  } else {
    attn_fwd_fb<<<dim3(512), dim3(256), 0, stream>>>(Q, K, V, O);
  }
}